// Round 1
// baseline (571.977 us; speedup 1.0000x reference)
//
#include <hip/hip_runtime.h>

typedef __attribute__((ext_vector_type(8))) short bf16x8;
typedef __attribute__((ext_vector_type(4))) float f32x4;
typedef __attribute__((ext_vector_type(4))) unsigned short us4;
typedef unsigned short u16;

#define MB (1024*1024)

__device__ __forceinline__ u16 f2bf(float f) {
    unsigned u = __float_as_uint(f);
    unsigned r = (u + 0x7fffu + ((u >> 16) & 1u)) >> 16;
    return (u16)r;
}

__device__ __forceinline__ f32x4 mfma16(bf16x8 a, bf16x8 b, f32x4 c) {
    return __builtin_amdgcn_mfma_f32_16x16x32_bf16(a, b, c, 0, 0, 0);
}

__device__ __forceinline__ void gload16(const void* g, void* l) {
    __builtin_amdgcn_global_load_lds(
        (__attribute__((address_space(1))) void*)(unsigned long long)g,
        (__attribute__((address_space(3))) void*)l, 16, 0, 0);
}

// ---------------- x -> bf16 ----------------
__global__ __launch_bounds__(256) void k_cvtx(const float* __restrict__ x, u16* __restrict__ xb) {
    const long long i = (long long)blockIdx.x * 256 + threadIdx.x;
    const float4* xp = (const float4*)x;
    float4 a = xp[i*2], b = xp[i*2+1];
    bf16x8 o;
    o[0]=(short)f2bf(a.x); o[1]=(short)f2bf(a.y); o[2]=(short)f2bf(a.z); o[3]=(short)f2bf(a.w);
    o[4]=(short)f2bf(b.x); o[5]=(short)f2bf(b.y); o[6]=(short)f2bf(b.z); o[7]=(short)f2bf(b.w);
    *(bf16x8*)&xb[i*8] = o;
}

// ---------------- W (K x N) -> Wt bf16 (N x K) ----------------
__global__ __launch_bounds__(256) void k_wtcvt(const float* __restrict__ W0, const float* __restrict__ W1,
                                               const float* __restrict__ W2, const float* __restrict__ W3,
                                               u16* __restrict__ wt) {
    __shared__ float tl[32][33];
    const int t = threadIdx.x, z = blockIdx.z;
    const float* W = (z==0)?W0:(z==1)?W1:(z==2)?W2:W3;
    const int k0 = blockIdx.x*32, n0 = blockIdx.y*32;
    const int r = t >> 3, c4 = (t & 7) * 4;
    float4 v = *(const float4*)&W[(long long)(k0+r)*1024 + n0 + c4];
    tl[r][c4] = v.x; tl[r][c4+1] = v.y; tl[r][c4+2] = v.z; tl[r][c4+3] = v.w;
    __syncthreads();
    us4 ov;
    ov[0] = f2bf(tl[c4+0][r]); ov[1] = f2bf(tl[c4+1][r]);
    ov[2] = f2bf(tl[c4+2][r]); ov[3] = f2bf(tl[c4+3][r]);
    *(us4*)&wt[((long long)z << 20) + (long long)(n0+r)*1024 + k0 + c4] = ov;
}

// ---------------- geo chain ----------------
__global__ __launch_bounds__(1024) void k_geo1(const float* __restrict__ geo, const float* __restrict__ W1,
                                               const float* __restrict__ b1, const float* __restrict__ lng,
                                               const float* __restrict__ lnb, float* __restrict__ hr) {
    const int b = blockIdx.x, j = threadIdx.x;
    float acc = b1[j];
    #pragma unroll 8
    for (int g = 0; g < 32; ++g) acc += geo[b*32+g] * W1[(long long)g*1024 + j];
    float s1 = acc, s2 = acc*acc;
    #pragma unroll
    for (int m = 1; m < 64; m <<= 1) { s1 += __shfl_xor(s1, m); s2 += __shfl_xor(s2, m); }
    __shared__ float r1[16], r2[16];
    __shared__ float mu_s, rv_s;
    const int wid = threadIdx.x >> 6, lid = threadIdx.x & 63;
    if (lid == 0) { r1[wid] = s1; r2[wid] = s2; }
    __syncthreads();
    if (threadIdx.x == 0) {
        float S1 = 0.f, S2 = 0.f;
        for (int i = 0; i < 16; ++i) { S1 += r1[i]; S2 += r2[i]; }
        float mu = S1 / 1024.f;
        float var = S2 / 1024.f - mu*mu;
        mu_s = mu; rv_s = rsqrtf(var + 1e-5f);
    }
    __syncthreads();
    float hv = (acc - mu_s) * rv_s * lng[j] + lnb[j];
    hr[b*1024 + j] = fmaxf(hv, 0.f);
}

__global__ __launch_bounds__(256) void k_geo2(const float* __restrict__ hr, const float* __restrict__ W2,
                                              const float* __restrict__ b2, float* __restrict__ ge) {
    const int b = blockIdx.x >> 2;
    const int j = (blockIdx.x & 3)*256 + threadIdx.x;
    __shared__ float hs[1024];
    #pragma unroll
    for (int i = 0; i < 4; ++i) hs[threadIdx.x*4 + i] = hr[b*1024 + threadIdx.x*4 + i];
    __syncthreads();
    float acc = b2[j];
    #pragma unroll 8
    for (int d = 0; d < 1024; ++d) acc += hs[d] * W2[(long long)d*1024 + j];
    ge[b*1024 + j] = acc;
}

__global__ __launch_bounds__(64) void k_geo3(const float* __restrict__ ge, const float* __restrict__ gmW,
                                             const float* __restrict__ gmb, float* __restrict__ qs) {
    const int t = threadIdx.x;
    const int b = t >> 4, hh = t & 15;
    float acc = gmb[hh];
    #pragma unroll 8
    for (int d = 0; d < 1024; ++d) acc += ge[b*1024 + d] * gmW[d*16 + hh];
    qs[t] = 0.125f * (1.f + 1.f/(1.f + __expf(-acc)));
}

// ---------------- QKV projection GEMM (m97 structure) ----------------
__global__ __launch_bounds__(256) void k_qkv_gemm(const u16* __restrict__ xb, const u16* __restrict__ wtq,
                                                  const float* __restrict__ bq, const float* __restrict__ bk,
                                                  const float* __restrict__ bv, u16* __restrict__ outq) {
    __shared__ u16 lA[128*64];
    __shared__ u16 lB[128*64];
    const int t = threadIdx.x, z = blockIdx.z;
    const int m0 = blockIdx.y * 128, n0 = blockIdx.x * 128;
    const u16* wt = wtq + (long long)z * (1024*1024);
    const float* bias = (z==0) ? bq : (z==1) ? bk : bv;
    u16* out = outq + (long long)z * 8388608;
    const int w = t >> 6, l = t & 63, lm = l & 15, lg = l >> 4;
    const int wr = (w >> 1) * 64, wc = (w & 1) * 64;
    f32x4 acc[4][4] = {};
    const char* gA = (const char*)xb + (long long)(m0 + (t>>3))*2048 + (t&7)*16;
    const char* gB = (const char*)wt + (long long)(n0 + (t>>3))*2048 + (t&7)*16;
    char* lAp = (char*)lA + t*16;
    char* lBp = (char*)lB + t*16;
    for (int k0 = 0; k0 < 1024; k0 += 64) {
        #pragma unroll
        for (int i = 0; i < 4; ++i) {
            gload16(gA + (long long)i*32*2048, lAp + i*4096);
            gload16(gB + (long long)i*32*2048, lBp + i*4096);
        }
        gA += 128; gB += 128;
        __syncthreads();
        #pragma unroll
        for (int kk = 0; kk < 2; ++kk) {
            bf16x8 af[4], bfr[4];
            #pragma unroll
            for (int mi = 0; mi < 4; ++mi)
                af[mi] = *(const bf16x8*)((const char*)lA + (wr + mi*16 + lm)*128 + kk*64 + lg*16);
            #pragma unroll
            for (int ni = 0; ni < 4; ++ni)
                bfr[ni] = *(const bf16x8*)((const char*)lB + (wc + ni*16 + lm)*128 + kk*64 + lg*16);
            #pragma unroll
            for (int mi = 0; mi < 4; ++mi)
                #pragma unroll
                for (int ni = 0; ni < 4; ++ni)
                    acc[mi][ni] = mfma16(af[mi], bfr[ni], acc[mi][ni]);
        }
        __syncthreads();
    }
    #pragma unroll
    for (int ni = 0; ni < 4; ++ni) {
        const int n = n0 + wc + ni*16 + lm;
        const float bn = bias[n];
        const int hh = n >> 6, d = n & 63;
        #pragma unroll
        for (int mi = 0; mi < 4; ++mi) {
            #pragma unroll
            for (int r = 0; r < 4; ++r) {
                const int m = m0 + wr + mi*16 + lg*4 + r;
                const int b = m >> 11, s = m & 2047;
                out[(((long long)b*16 + hh)*2048 + s)*64 + d] = f2bf(acc[mi][ni][r] + bn);
            }
        }
    }
}

// ---------------- V [bh][s][d] -> Vt [bh][d][s] ----------------
__global__ __launch_bounds__(256) void k_vtrans(const u16* __restrict__ vb, u16* __restrict__ vt) {
    __shared__ u16 tl[64][40];
    const int t = threadIdx.x;
    const int bh = blockIdx.z, s0 = blockIdx.y*64, d0 = blockIdx.x*32;
    const u16* vsrc = vb + (long long)bh*2048*64;
    {
        const int sl = t >> 2, dg = t & 3;
        bf16x8 v = *(const bf16x8*)&vsrc[(long long)(s0+sl)*64 + d0 + dg*8];
        *(bf16x8*)&tl[sl][dg*8] = v;
    }
    __syncthreads();
    {
        const int dl = t >> 3, sg = t & 7;
        bf16x8 o;
        #pragma unroll
        for (int j = 0; j < 8; ++j) o[j] = (short)tl[sg*8+j][dl];
        *(bf16x8*)&vt[((long long)bh*64 + d0+dl)*2048 + s0 + sg*8] = o;
    }
}

// ---------------- fused attention ----------------
__global__ __launch_bounds__(256) void k_attn(const u16* __restrict__ Qb, const u16* __restrict__ Kb,
                                              const u16* __restrict__ Vt, const float* __restrict__ qsv,
                                              float* __restrict__ attn_out, u16* __restrict__ ctxb) {
    __shared__ u16 lK[128*64];   // [key][d], xor-swizzled
    __shared__ u16 lV[64*128];   // [d][key], xor-swizzled
    __shared__ u16 lP[128*128];  // [q][key], xor-swizzled

    const int nl = blockIdx.x;
    const int ob = (nl & 7)*128 + (nl >> 3);      // XCD-chunked swizzle (1024 % 8 == 0)
    const int bh = ob >> 4, qt = ob & 15;
    const int t = threadIdx.x, w = t >> 6, l = t & 63, lm = l & 15, lg = l >> 4;
    const int q0 = qt * 128;
    const float qs = qsv[bh];

    const char* KB = (const char*)Kb + (long long)bh * (2048*64*2);
    const char* VB = (const char*)Vt + (long long)bh * (2048*64*2);

    bf16x8 qf[2][2];
    {
        const char* QB = (const char*)Qb + (long long)bh * (2048*64*2);
        #pragma unroll
        for (int ms = 0; ms < 2; ++ms)
            #pragma unroll
            for (int kc = 0; kc < 2; ++kc)
                qf[ms][kc] = *(const bf16x8*)(QB + (long long)(q0 + w*32 + ms*16 + lm)*128 + kc*64 + lg*16);
    }

    int koff[4], voff[4], loff[4];
    #pragma unroll
    for (int i = 0; i < 4; ++i) {
        int off = i*4096 + t*16;
        loff[i] = off;
        int rowk = off >> 7, pck = off & 127;
        koff[i] = rowk*128 + (pck ^ ((rowk & 7) << 4));
        int rowv = off >> 8, pcv = off & 255;
        voff[i] = rowv*4096 + (pcv ^ ((rowv & 7) << 4));
    }

    // ---- sweep 1: row sums of exp(L) ----
    float lsum[2][4] = {};
    for (int kt = 0; kt < 16; ++kt) {
        #pragma unroll
        for (int i = 0; i < 4; ++i)
            gload16(KB + kt*16384 + koff[i], (char*)lK + loff[i]);
        __syncthreads();
        #pragma unroll
        for (int ns = 0; ns < 8; ++ns) {
            const int rowb = ns*16 + lm;
            const int tag = (rowb & 7) << 4;
            bf16x8 kf0 = *(const bf16x8*)((const char*)lK + rowb*128 + ((lg*16) ^ tag));
            bf16x8 kf1 = *(const bf16x8*)((const char*)lK + rowb*128 + ((64 + lg*16) ^ tag));
            #pragma unroll
            for (int ms = 0; ms < 2; ++ms) {
                f32x4 acc = {};
                acc = mfma16(qf[ms][0], kf0, acc);
                acc = mfma16(qf[ms][1], kf1, acc);
                #pragma unroll
                for (int r = 0; r < 4; ++r)
                    lsum[ms][r] += __expf(acc[r] * qs);
            }
        }
        __syncthreads();
    }
    float invl[2][4];
    #pragma unroll
    for (int ms = 0; ms < 2; ++ms)
        #pragma unroll
        for (int r = 0; r < 4; ++r) {
            float v = lsum[ms][r];
            v += __shfl_xor(v, 1); v += __shfl_xor(v, 2);
            v += __shfl_xor(v, 4); v += __shfl_xor(v, 8);
            invl[ms][r] = 1.f / v;
        }

    // ---- sweep 2: recompute, write attn, PV ----
    f32x4 cacc[2][4] = {};
    float* aout = attn_out + (long long)bh*2048*2048 + (long long)(q0 + w*32)*2048;
    for (int kt = 0; kt < 16; ++kt) {
        #pragma unroll
        for (int i = 0; i < 4; ++i)
            gload16(KB + kt*16384 + koff[i], (char*)lK + loff[i]);
        #pragma unroll
        for (int i = 0; i < 4; ++i)
            gload16(VB + kt*256 + voff[i], (char*)lV + loff[i]);
        __syncthreads();

        #pragma unroll
        for (int ns = 0; ns < 8; ++ns) {
            const int rowb = ns*16 + lm;
            const int tag = (rowb & 7) << 4;
            bf16x8 kf0 = *(const bf16x8*)((const char*)lK + rowb*128 + ((lg*16) ^ tag));
            bf16x8 kf1 = *(const bf16x8*)((const char*)lK + rowb*128 + ((64 + lg*16) ^ tag));
            #pragma unroll
            for (int ms = 0; ms < 2; ++ms) {
                f32x4 acc = {};
                acc = mfma16(qf[ms][0], kf0, acc);
                acc = mfma16(qf[ms][1], kf1, acc);
                #pragma unroll
                for (int r = 0; r < 4; ++r) {
                    const float p = __expf(acc[r]*qs) * invl[ms][r];
                    const int row = ms*16 + lg*4 + r;
                    __builtin_nontemporal_store(p, &aout[(long long)row*2048 + kt*128 + ns*16 + lm]);
                    const int prow = w*32 + row;
                    *(u16*)((char*)lP + prow*256 + (((ns*16 + lm)*2) ^ ((prow & 7) << 4))) = f2bf(p);
                }
            }
        }
        // PV (each wave reads only its own lP rows; same-wave RAW handled by lgkmcnt)
        #pragma unroll
        for (int ks = 0; ks < 4; ++ks) {
            bf16x8 pa[2];
            #pragma unroll
            for (int ms = 0; ms < 2; ++ms) {
                const int prow = w*32 + ms*16 + lm;
                pa[ms] = *(const bf16x8*)((const char*)lP + prow*256 + ((ks*64 + lg*16) ^ ((prow & 7) << 4)));
            }
            #pragma unroll
            for (int dn = 0; dn < 4; ++dn) {
                const int rowv = dn*16 + lm;
                bf16x8 vf = *(const bf16x8*)((const char*)lV + rowv*256 + ((ks*64 + lg*16) ^ ((rowv & 7) << 4)));
                cacc[0][dn] = mfma16(pa[0], vf, cacc[0][dn]);
                cacc[1][dn] = mfma16(pa[1], vf, cacc[1][dn]);
            }
        }
        __syncthreads();
    }

    const int b = bh >> 4, hh = bh & 15;
    #pragma unroll
    for (int ms = 0; ms < 2; ++ms)
        #pragma unroll
        for (int dn = 0; dn < 4; ++dn)
            #pragma unroll
            for (int r = 0; r < 4; ++r) {
                const int q = q0 + w*32 + ms*16 + lg*4 + r;
                ctxb[(((long long)b*2048 + q)*16 + hh)*64 + dn*16 + lm] = f2bf(cacc[ms][dn][r]);
            }
}

// ---------------- output projection ----------------
__global__ __launch_bounds__(256) void k_o_gemm(const u16* __restrict__ ab, const u16* __restrict__ wt,
                                                const float* __restrict__ bo, float* __restrict__ outf) {
    __shared__ u16 lA[128*64];
    __shared__ u16 lB[128*64];
    const int t = threadIdx.x;
    const int m0 = blockIdx.y * 128, n0 = blockIdx.x * 128;
    const int w = t >> 6, l = t & 63, lm = l & 15, lg = l >> 4;
    const int wr = (w >> 1) * 64, wc = (w & 1) * 64;
    f32x4 acc[4][4] = {};
    const char* gA = (const char*)ab + (long long)(m0 + (t>>3))*2048 + (t&7)*16;
    const char* gB = (const char*)wt + (long long)(n0 + (t>>3))*2048 + (t&7)*16;
    char* lAp = (char*)lA + t*16;
    char* lBp = (char*)lB + t*16;
    for (int k0 = 0; k0 < 1024; k0 += 64) {
        #pragma unroll
        for (int i = 0; i < 4; ++i) {
            gload16(gA + (long long)i*32*2048, lAp + i*4096);
            gload16(gB + (long long)i*32*2048, lBp + i*4096);
        }
        gA += 128; gB += 128;
        __syncthreads();
        #pragma unroll
        for (int kk = 0; kk < 2; ++kk) {
            bf16x8 af[4], bfr[4];
            #pragma unroll
            for (int mi = 0; mi < 4; ++mi)
                af[mi] = *(const bf16x8*)((const char*)lA + (wr + mi*16 + lm)*128 + kk*64 + lg*16);
            #pragma unroll
            for (int ni = 0; ni < 4; ++ni)
                bfr[ni] = *(const bf16x8*)((const char*)lB + (wc + ni*16 + lm)*128 + kk*64 + lg*16);
            #pragma unroll
            for (int mi = 0; mi < 4; ++mi)
                #pragma unroll
                for (int ni = 0; ni < 4; ++ni)
                    acc[mi][ni] = mfma16(af[mi], bfr[ni], acc[mi][ni]);
        }
        __syncthreads();
    }
    #pragma unroll
    for (int ni = 0; ni < 4; ++ni) {
        const int n = n0 + wc + ni*16 + lm;
        const float bn = bo[n];
        #pragma unroll
        for (int mi = 0; mi < 4; ++mi) {
            #pragma unroll
            for (int r = 0; r < 4; ++r) {
                const int m = m0 + wr + mi*16 + lg*4 + r;
                outf[(long long)m*1024 + n] = acc[mi][ni][r] + bn;
            }
        }
    }
}

extern "C" void kernel_launch(void* const* d_in, const int* in_sizes, int n_in,
                              void* d_out, int out_size, void* d_ws, size_t ws_size,
                              hipStream_t stream) {
    const float* x    = (const float*)d_in[0];
    const float* geo  = (const float*)d_in[1];
    const float* Wq   = (const float*)d_in[2];
    const float* bq   = (const float*)d_in[3];
    const float* Wk   = (const float*)d_in[4];
    const float* bk   = (const float*)d_in[5];
    const float* Wv   = (const float*)d_in[6];
    const float* bv   = (const float*)d_in[7];
    const float* Wo   = (const float*)d_in[8];
    const float* bo   = (const float*)d_in[9];
    const float* geW1 = (const float*)d_in[10];
    const float* geb1 = (const float*)d_in[11];
    const float* lng  = (const float*)d_in[12];
    const float* lnb  = (const float*)d_in[13];
    const float* geW2 = (const float*)d_in[14];
    const float* geb2 = (const float*)d_in[15];
    const float* gmW  = (const float*)d_in[16];
    const float* gmb  = (const float*)d_in[17];

    char* ws = (char*)d_ws;
    u16* xb   = (u16*)(ws + 0);                 // 16 MB
    u16* wt   = (u16*)(ws + 16*(size_t)MB);     // 4 x 2 MB (q,k,v,o transposed bf16)
    u16* qkv  = (u16*)(ws + 24*(size_t)MB);     // Q,K,V each 16 MB
    u16* Qb   = qkv;
    u16* Kb   = (u16*)(ws + 40*(size_t)MB);
    u16* Vb   = (u16*)(ws + 56*(size_t)MB);
    u16* Vt   = (u16*)(ws + 72*(size_t)MB);
    u16* ctx  = Vb;                              // reuse V-raw region after transpose
    float* hr = (float*)(ws + 88*(size_t)MB);
    float* ge = (float*)(ws + 88*(size_t)MB + 65536);
    float* qsb= (float*)(ws + 88*(size_t)MB + 131072);

    float* outf = (float*)d_out;
    float* attn = outf + 8388608;

    hipLaunchKernelGGL(k_cvtx,    dim3(4096),      dim3(256),  0, stream, x, xb);
    hipLaunchKernelGGL(k_wtcvt,   dim3(32,32,4),   dim3(256),  0, stream, Wq, Wk, Wv, Wo, wt);
    hipLaunchKernelGGL(k_geo1,    dim3(4),         dim3(1024), 0, stream, geo, geW1, geb1, lng, lnb, hr);
    hipLaunchKernelGGL(k_geo2,    dim3(16),        dim3(256),  0, stream, hr, geW2, geb2, ge);
    hipLaunchKernelGGL(k_geo3,    dim3(1),         dim3(64),   0, stream, ge, gmW, gmb, qsb);
    hipLaunchKernelGGL(k_qkv_gemm,dim3(8,64,3),    dim3(256),  0, stream, xb, wt, bq, bk, bv, qkv);
    hipLaunchKernelGGL(k_vtrans,  dim3(2,32,64),   dim3(256),  0, stream, Vb, Vt);
    hipLaunchKernelGGL(k_attn,    dim3(1024),      dim3(256),  0, stream, Qb, Kb, Vt, qsb, attn, ctx);
    hipLaunchKernelGGL(k_o_gemm,  dim3(8,64),      dim3(256),  0, stream, ctx, wt + 3*1048576, bo, outf);
}